// Round 2
// baseline (1488.417 us; speedup 1.0000x reference)
//
#include <hip/hip_runtime.h>
#include <stdint.h>

#define XY 32
#define ZS 16
#define NST 16384          // N = XY*XY*ZS
#define NMASK 16383
#define VOC 10000
#define BB 32
#define TT 64
#define LL 16
#define HALO 32            // covers +-1 and +-32 neighbor reads without masking
#define BUFSZ (NST + 2 * HALO)   // 16448 floats per score buffer

#define LOG2E 1.4426950408889634f
#define LN2F  0.6931471805599453f

__device__ __forceinline__ float fexp2(float x) {
#if __has_builtin(__builtin_amdgcn_exp2f)
  return __builtin_amdgcn_exp2f(x);
#else
  return exp2f(x);
#endif
}
__device__ __forceinline__ float flog2(float x) {
#if __has_builtin(__builtin_amdgcn_logf)
  return __builtin_amdgcn_logf(x);
#else
  return log2f(x);
#endif
}

__device__ __forceinline__ float waveMax(float v) {
  #pragma unroll
  for (int o = 32; o >= 1; o >>= 1) v = fmaxf(v, __shfl_xor(v, o, 64));
  return v;
}
__device__ __forceinline__ float waveSum(float v) {
  #pragma unroll
  for (int o = 32; o >= 1; o >>= 1) v += __shfl_xor(v, o, 64);
  return v;
}

// Repack tokens: stories[b][t][l] (int32) -> tok16[(t*32+b)*16 + l] (u16).
__global__ __launch_bounds__(256) void tok_conv(const int* __restrict__ st,
                                                unsigned short* __restrict__ tok16) {
  int i = blockIdx.x * 256 + threadIdx.x;
  if (i >= BB * TT * LL) return;
  int l = i & 15;
  int tb = i >> 4;
  int b = tb & 31;
  int t = tb >> 5;
  tok16[i] = (unsigned short)st[b * (TT * LL) + t * LL + l];
}

// Transition softmax: Tn[n*8+k] = softmax(trans[n,:])[k], pad slot 7 = 0.
__global__ __launch_bounds__(256) void prep_trans(const float* __restrict__ tr,
                                                  float* __restrict__ Tn) {
  int n = blockIdx.x * 256 + threadIdx.x;
  if (n >= NST) return;
  float v[7];
  float m = -3.4e38f;
  #pragma unroll
  for (int k = 0; k < 7; ++k) { v[k] = tr[n * 7 + k]; m = fmaxf(m, v[k]); }
  float s = 0.f;
  #pragma unroll
  for (int k = 0; k < 7; ++k) { v[k] = fexp2((v[k] - m) * LOG2E); s += v[k]; }
  float inv = 1.0f / s;
  #pragma unroll
  for (int k = 0; k < 7; ++k) Tn[n * 8 + k] = v[k] * inv;
  Tn[n * 8 + 7] = 0.f;
}

// lse_p[0] = ln-domain logsumexp of prior (single block).
__global__ __launch_bounds__(256) void lse_prior(const float* __restrict__ prior,
                                                 float* __restrict__ lse_p) {
  int tid = threadIdx.x;
  __shared__ float sred[8];
  float lmax = -3.4e38f;
  for (int n = tid; n < NST; n += 256) lmax = fmaxf(lmax, prior[n]);
  float wm = waveMax(lmax);
  if ((tid & 63) == 0) sred[tid >> 6] = wm;
  __syncthreads();
  float bm = fmaxf(fmaxf(sred[0], sred[1]), fmaxf(sred[2], sred[3]));
  float ls = 0.f;
  for (int n = tid; n < NST; n += 256) ls += fexp2((prior[n] - bm) * LOG2E);
  float ws = waveSum(ls);
  if ((tid & 63) == 0) sred[4 + (tid >> 6)] = ws;
  __syncthreads();
  if (tid == 0)
    lse_p[0] = bm + flog2(sred[4] + sred[5] + sred[6] + sred[7]) * LN2F;
}

// One WG per state n: stage emis row in LDS, compute row LSE, gather token
// sums for all (t,b). Output em[n][i], i=t*32+b, PRE-SCALED by LOG2E
// (log2-domain for the recursion).
__global__ __launch_bounds__(256) void emis_kernel(const float* __restrict__ emis,
                                                   const unsigned short* __restrict__ tok16,
                                                   float* __restrict__ em) {
  const int n = blockIdx.x;
  const int tid = threadIdx.x;
  __shared__ float row[VOC];
  __shared__ float sred[8];

  const float4* rp = (const float4*)(emis + (size_t)n * VOC);
  float4 regs[10];
  float lmax = -3.4e38f;
  #pragma unroll
  for (int it = 0; it < 10; ++it) {
    int i = tid + it * 256;
    if (i < VOC / 4) {
      float4 v = rp[i];
      regs[it] = v;
      ((float4*)row)[i] = v;
      lmax = fmaxf(lmax, fmaxf(fmaxf(v.x, v.y), fmaxf(v.z, v.w)));
    }
  }
  float wm = waveMax(lmax);
  if ((tid & 63) == 0) sred[tid >> 6] = wm;
  __syncthreads();
  float bm = fmaxf(fmaxf(sred[0], sred[1]), fmaxf(sred[2], sred[3]));

  float ls = 0.f;
  #pragma unroll
  for (int it = 0; it < 10; ++it) {
    int i = tid + it * 256;
    if (i < VOC / 4) {
      float4 v = regs[it];
      ls += fexp2((v.x - bm) * LOG2E);
      ls += fexp2((v.y - bm) * LOG2E);
      ls += fexp2((v.z - bm) * LOG2E);
      ls += fexp2((v.w - bm) * LOG2E);
    }
  }
  float wsum = waveSum(ls);
  if ((tid & 63) == 0) sred[4 + (tid >> 6)] = wsum;
  __syncthreads();
  float lse = bm + flog2(sred[4] + sred[5] + sred[6] + sred[7]) * LN2F;
  float sub = (float)LL * lse;

  for (int i = tid; i < TT * BB; i += 256) {
    const uint4* tp = (const uint4*)(tok16 + (size_t)i * 16);
    uint4 w0 = tp[0];
    uint4 w1 = tp[1];
    float s = row[w0.x & 0xFFFF] + row[w0.x >> 16]
            + row[w0.y & 0xFFFF] + row[w0.y >> 16]
            + row[w0.z & 0xFFFF] + row[w0.z >> 16]
            + row[w0.w & 0xFFFF] + row[w0.w >> 16]
            + row[w1.x & 0xFFFF] + row[w1.x >> 16]
            + row[w1.y & 0xFFFF] + row[w1.y >> 16]
            + row[w1.z & 0xFFFF] + row[w1.z >> 16]
            + row[w1.w & 0xFFFF] + row[w1.w >> 16];
    em[(size_t)n * (TT * BB) + i] = (s - sub) * LOG2E;
  }
}

// Transpose em[n][i] (16384 x 2048) -> em2[i][n] (2048 x 16384).
__global__ __launch_bounds__(256) void transpose_em(const float* __restrict__ em,
                                                    float* __restrict__ em2) {
  __shared__ float tile[64][65];
  const int i0 = blockIdx.x * 64;   // 32 tiles
  const int n0 = blockIdx.y * 64;   // 256 tiles
  const int tx = threadIdx.x & 63;
  const int ty = threadIdx.x >> 6;  // 0..3
  #pragma unroll
  for (int r = 0; r < 16; ++r) {
    int nr = ty + 4 * r;
    tile[nr][tx] = em[(size_t)(n0 + nr) * (TT * BB) + i0 + tx];
  }
  __syncthreads();
  #pragma unroll
  for (int r = 0; r < 16; ++r) {
    int ir = ty + 4 * r;
    em2[(size_t)(i0 + ir) * NST + n0 + tx] = tile[tx][ir];
  }
}

// Whole recursion for one batch b in one workgroup. Scores live in LDS
// (double-buffered, +-32 halo). All values in log2 domain.
__global__ __launch_bounds__(1024) void recursion_kernel(const float* __restrict__ em2,
                                                         const float* __restrict__ Tn8,
                                                         const float* __restrict__ prior,
                                                         const float* __restrict__ lse_p,
                                                         float* __restrict__ out) {
  extern __shared__ float lds[];
  float* buf0 = lds;           // BUFSZ floats, holds even t
  float* buf1 = lds + BUFSZ;   // holds odd t
  const int b = blockIdx.x;
  const int tid = threadIdx.x;

  // t = 0: scores0 = em2[b] + prior*LOG2E
  {
    const float* e0 = em2 + ((size_t)b << 14);
    #pragma unroll
    for (int s = 0; s < 16; ++s) {
      int n = tid + (s << 10);
      float v = e0[n] + prior[n] * LOG2E;
      buf0[HALO + n] = v;
      if (n < HALO) buf0[HALO + NST + n] = v;
      if (n >= NST - HALO) buf0[n - (NST - HALO)] = v;
    }
  }
  __syncthreads();

  for (int t = 1; t < TT; ++t) {
    const float* prev = (t & 1) ? buf0 : buf1;
    float* cur = (t & 1) ? buf1 : buf0;
    const float* e = em2 + ((size_t)(t * BB + b) << 14);
    // rolling regs give prev[n-1024] / prev[n-2048] for s>=2 for free
    float pm1 = prev[HALO + ((tid - 1024) & NMASK)];
    float pm2 = prev[HALO + ((tid - 2048) & NMASK)];
    #pragma unroll
    for (int s = 0; s < 16; ++s) {
      int n = tid + (s << 10);
      float p0 = prev[HALO + n];
      float a1 = prev[HALO + n - 1];    // offset +1  -> prev[n-1]
      float a2 = prev[HALO + n + 1];    // offset -1  -> prev[n+1]
      float a3 = prev[HALO + n - 32];   // offset +32 -> prev[n-32]
      float a4 = prev[HALO + n + 32];   // offset -32 -> prev[n+32]
      float p5 = pm1;                   // prev[n-1024]
      float p6 = pm2;                   // prev[n-2048]
      const float4* tp = (const float4*)(Tn8 + ((size_t)n << 3));
      float4 ta = tp[0];
      float4 tb = tp[1];
      float m = fmaxf(fmaxf(fmaxf(p0, a1), fmaxf(a2, a3)),
                      fmaxf(fmaxf(a4, p5), p6));
      float ssum = ta.x * fexp2(p0 - m) + ta.y * fexp2(a1 - m)
                 + ta.z * fexp2(a2 - m) + ta.w * fexp2(a3 - m)
                 + tb.x * fexp2(a4 - m) + tb.y * fexp2(p5 - m)
                 + tb.z * fexp2(p6 - m);
      float v = e[n] + m + flog2(ssum);
      cur[HALO + n] = v;
      if (n < HALO) cur[HALO + NST + n] = v;
      if (n >= NST - HALO) cur[n - (NST - HALO)] = v;
      pm2 = pm1;
      pm1 = p0;
    }
    __syncthreads();
  }

  // Final LSE over buf1 (t=63 is odd). buf0 is dead -> use as scratch.
  float lm = -3.4e38f;
  #pragma unroll
  for (int s = 0; s < 16; ++s)
    lm = fmaxf(lm, buf1[HALO + tid + (s << 10)]);
  lm = waveMax(lm);
  if ((tid & 63) == 0) buf0[tid >> 6] = lm;
  __syncthreads();
  float bm = buf0[0];
  #pragma unroll
  for (int k = 1; k < 16; ++k) bm = fmaxf(bm, buf0[k]);
  float ls = 0.f;
  #pragma unroll
  for (int s = 0; s < 16; ++s)
    ls += fexp2(buf1[HALO + tid + (s << 10)] - bm);
  ls = waveSum(ls);
  if ((tid & 63) == 0) buf0[16 + (tid >> 6)] = ls;
  __syncthreads();
  if (tid == 0) {
    float s = 0.f;
    #pragma unroll
    for (int k = 0; k < 16; ++k) s += buf0[16 + k];
    out[b] = LN2F * (bm + flog2(s)) - lse_p[0];
  }
}

extern "C" void kernel_launch(void* const* d_in, const int* in_sizes, int n_in,
                              void* d_out, int out_size, void* d_ws, size_t ws_size,
                              hipStream_t stream) {
  const int* stories  = (const int*)d_in[0];
  const float* trans  = (const float*)d_in[3];
  const float* emis   = (const float*)d_in[4];
  const float* prior  = (const float*)d_in[5];
  float* out = (float*)d_out;

  char* ws = (char*)d_ws;
  float* em  = (float*)ws;                                   // 134.2 MB
  float* em2 = em + (size_t)NST * TT * BB;                   // 134.2 MB
  float* Tn  = em2 + (size_t)NST * TT * BB;                  // 512 KB
  unsigned short* tok16 = (unsigned short*)(Tn + (size_t)NST * 8);  // 64 KB
  float* lse_p = (float*)(tok16 + (size_t)BB * TT * LL);     // 4 B

  tok_conv<<<(BB * TT * LL + 255) / 256, 256, 0, stream>>>(stories, tok16);
  prep_trans<<<NST / 256, 256, 0, stream>>>(trans, Tn);
  lse_prior<<<1, 256, 0, stream>>>(prior, lse_p);
  emis_kernel<<<NST, 256, 0, stream>>>(emis, tok16, em);
  transpose_em<<<dim3(TT * BB / 64, NST / 64), 256, 0, stream>>>(em, em2);

  size_t dynlds = (size_t)2 * BUFSZ * sizeof(float);  // 131584 B
  hipFuncSetAttribute((const void*)recursion_kernel,
                      hipFuncAttributeMaxDynamicSharedMemorySize, (int)dynlds);
  recursion_kernel<<<BB, 1024, dynlds, stream>>>(em2, Tn, prior, lse_p, out);
}